// Round 9
// baseline (2412.408 us; speedup 1.0000x reference)
//
#include <hip/hip_runtime.h>
#include <hip/hip_bf16.h>
#include <cstdint>
#include <cstddef>

#define HH 1024
#define BB 8
#define TT 2048
#define MM (BB*TT)   // 16384
#define CC 128       // wkv chunks
#define LL (TT/CC)   // 16 steps per chunk

typedef __attribute__((ext_vector_type(8))) short bf16x8;
typedef __attribute__((ext_vector_type(8))) unsigned short u16x8;
typedef __attribute__((ext_vector_type(16))) float f32x16;

__device__ __forceinline__ unsigned short f2bf(float f) {
  union { float f; unsigned u; } v; v.f = f;
  return (unsigned short)((v.u + 0x7fffu + ((v.u >> 16) & 1u)) >> 16);  // RNE
}
__device__ __forceinline__ float bf2f(unsigned short s) {
  union { float f; unsigned u; } v; v.u = ((unsigned)s) << 16;
  return v.f;
}

__device__ __forceinline__ void load_lds16(const void* g, void* l) {
  __builtin_amdgcn_global_load_lds((const __attribute__((address_space(1))) void*)g,
                                   (__attribute__((address_space(3))) void*)l,
                                   16, 0, 0);
}

// ---------------- weight fp32 -> bf16 ----------------
__global__ __launch_bounds__(256) void conv_w(const float* __restrict__ Wk,
    const float* __restrict__ Wv, const float* __restrict__ Wr,
    const float* __restrict__ Wo, unsigned short* __restrict__ dst) {
  const int i = (blockIdx.x * 256 + threadIdx.x) * 4;
  const float* src = blockIdx.y == 0 ? Wk : blockIdx.y == 1 ? Wv : blockIdx.y == 2 ? Wr : Wo;
  const float4 v = *(const float4*)(src + i);
  ushort4 o; o.x = f2bf(v.x); o.y = f2bf(v.y); o.z = f2bf(v.z); o.w = f2bf(v.w);
  *(ushort4*)(dst + (size_t)blockIdx.y * HH * HH + i) = o;
}

// ---------------- time-shift + mix -> bf16 kin/vin/rin ----------------
__global__ __launch_bounds__(256) void mix_kernel(const float* __restrict__ x,
    const float* __restrict__ tmk, const float* __restrict__ tmv, const float* __restrict__ tmr,
    unsigned short* __restrict__ kin, unsigned short* __restrict__ vin,
    unsigned short* __restrict__ rin) {
  const int gid = blockIdx.x * 256 + threadIdx.x;
  const size_t e0 = (size_t)gid * 4;
  const int h = (int)(e0 & (HH - 1));
  const int t = (int)((e0 >> 10) & (TT - 1));
  const float4 xv = *(const float4*)(x + e0);
  float4 sv = make_float4(0.f, 0.f, 0.f, 0.f);
  if (t != 0) sv = *(const float4*)(x + e0 - HH);
  const float4 k4 = *(const float4*)(tmk + h);
  const float4 v4 = *(const float4*)(tmv + h);
  const float4 r4 = *(const float4*)(tmr + h);
  ushort4 ko, vo, ro;
  ko.x = f2bf(sv.x + k4.x * (xv.x - sv.x)); ko.y = f2bf(sv.y + k4.y * (xv.y - sv.y));
  ko.z = f2bf(sv.z + k4.z * (xv.z - sv.z)); ko.w = f2bf(sv.w + k4.w * (xv.w - sv.w));
  vo.x = f2bf(sv.x + v4.x * (xv.x - sv.x)); vo.y = f2bf(sv.y + v4.y * (xv.y - sv.y));
  vo.z = f2bf(sv.z + v4.z * (xv.z - sv.z)); vo.w = f2bf(sv.w + v4.w * (xv.w - sv.w));
  ro.x = f2bf(sv.x + r4.x * (xv.x - sv.x)); ro.y = f2bf(sv.y + r4.y * (xv.y - sv.y));
  ro.z = f2bf(sv.z + r4.z * (xv.z - sv.z)); ro.w = f2bf(sv.w + r4.w * (xv.w - sv.w));
  *(ushort4*)(kin + e0) = ko;
  *(ushort4*)(vin + e0) = vo;
  *(ushort4*)(rin + e0) = ro;
}

// ===== 256x256 GEMM core, r9: 32x32 frags + single-buffer 64KB LDS + 2 wg/CU =====
// r8 post-mortem: 32x32 frags halve LDS-read traffic (floor 46-61us vs 92us for 16x16)
// but the 1 wg/CU 8-phase lockstep serialized stage-waits/barriers/reads/MFMA -> 142us.
// r9 mechanism: INTER-WG overlap (m114). Single-buffered BK=64 tile -> LDS 64KB ->
// 2 wgs/CU (launch_bounds(512,4)); one wg's stage+VM0+barrier stall hides under the
// other wg's compute. Schedule: per K-tile only 2 barriers:
//   [buffer holds tile t]  compute 4 K16 substeps (no internal barriers - buffer is
//   stable, compiler emits progressive lgkmcnt)  BAR  stage tile t+1  VM0  BAR
// Reads/staging/3-bit swizzle and packed C^T epilogue carried from r8 (refcheck'd).

#define BAR()   do { asm volatile("" ::: "memory"); __builtin_amdgcn_s_barrier(); \
                     asm volatile("" ::: "memory"); } while (0)
#define VM0()   asm volatile("s_waitcnt vmcnt(0)" ::: "memory")
#define PRIO1() __builtin_amdgcn_s_setprio(1)
#define PRIO0() __builtin_amdgcn_s_setprio(0)

__device__ __forceinline__ void stA(const unsigned short* __restrict__ Ag, int m0, int kt,
                                    unsigned short* buf, int h, int w, int rl, int scol) {
#pragma unroll
  for (int l = 0; l < 2; ++l) {
    const int row = l * 128 + h * 64 + w * 8;          // wave-uniform dest row base (0 mod 8)
    load_lds16(Ag + (size_t)(m0 + row + rl) * HH + kt + scol, buf + row * 64);
  }
}
__device__ __forceinline__ void stB(const unsigned short* __restrict__ Bg, int n0, int kt,
                                    unsigned short* buf, int h, int w, int rl, int scol) {
#pragma unroll
  for (int l = 0; l < 2; ++l) {
    const int row = (2 * (l * 2 + (w >> 2)) + h) * 32 + (w & 3) * 8;   // 0 mod 8
    load_lds16(Bg + (size_t)(n0 + row + rl) * HH + kt + scol, buf + row * 64);
  }
}

__device__ __forceinline__ bf16x8 rd1(const unsigned short* buf, int row, int kq, int swz) {
  return *(const bf16x8*)(buf + row * 64 + ((kq * 8) ^ swz));
}
// one K16-step's fragments: 6 ds_read_b128, consumption order
__device__ __forceinline__ void rdS(const unsigned short* bA, const unsigned short* bB,
                                    int wm, int wn, int l31, int kq, int swz,
                                    bf16x8 (&af)[4], bf16x8 (&bfr)[2]) {
  bfr[0] = rd1(bB, wn * 64 + l31, kq, swz);
  af[0]  = rd1(bA, wm * 128 + l31, kq, swz);
  bfr[1] = rd1(bB, wn * 64 + 32 + l31, kq, swz);
  af[1]  = rd1(bA, wm * 128 + 32 + l31, kq, swz);
  af[2]  = rd1(bA, wm * 128 + 64 + l31, kq, swz);
  af[3]  = rd1(bA, wm * 128 + 96 + l31, kq, swz);
}
// 8 MFMA of 32x32x16, swapped operands -> acc = C^T fragments. All independent.
__device__ __forceinline__ void mfmaS(f32x16 (&acc)[4][2], const bf16x8 (&af)[4],
                                      const bf16x8 (&bfr)[2]) {
#pragma unroll
  for (int mi = 0; mi < 4; ++mi)
#pragma unroll
    for (int nj = 0; nj < 2; ++nj)
      acc[mi][nj] = __builtin_amdgcn_mfma_f32_32x32x16_bf16(bfr[nj], af[mi],
                                                            acc[mi][nj], 0, 0, 0);
}

__device__ __forceinline__ void gemm256(const unsigned short* __restrict__ Ag,
                                        const unsigned short* __restrict__ Bg,
                                        const int m0, const int n0,
                                        unsigned short* As, unsigned short* Bs,
                                        f32x16 (&acc)[4][2]) {
  const int tid = threadIdx.x;
  const int lane = tid & 63;
  const int w = tid >> 6;
  const int wm = w >> 2, wn = w & 3;
  const int l31 = lane & 31, lh = lane >> 5;
  const int swz = (lane & 7) << 3;                 // read-side XOR (k-block ^= row&7)
  const int rl = lane >> 3;                        // stage dest row-in-8
  const int scol = ((lane & 7) ^ rl) * 8;          // pre-swizzled global source col
  bf16x8 af[4], bfr[2];

  // prologue: stage tile 0 (8 legs/wave); drain; barrier.
  stA(Ag, m0, 0, As, 0, w, rl, scol);
  stA(Ag, m0, 0, As, 1, w, rl, scol);
  stB(Bg, n0, 0, Bs, 0, w, rl, scol);
  stB(Bg, n0, 0, Bs, 1, w, rl, scol);
  VM0(); BAR();

#pragma unroll 1
  for (int t = 0; t < 16; ++t) {
    // compute the whole tile: 4 K16 substeps, no internal barriers
#pragma unroll
    for (int s = 0; s < 4; ++s) {
      rdS(As, Bs, wm, wn, l31, s * 2 + lh, swz, af, bfr);
      PRIO1(); mfmaS(acc, af, bfr); PRIO0();
    }
    BAR();                       // all of this wg's reads of tile t complete
    if (t < 15) {
      const int tn = (t + 1) * 64;
      stA(Ag, m0, tn, As, 0, w, rl, scol);
      stA(Ag, m0, tn, As, 1, w, rl, scol);
      stB(Bg, n0, tn, Bs, 0, w, rl, scol);
      stB(Bg, n0, tn, Bs, 1, w, rl, scol);
      VM0();                     // tile t+1 landed (stall hidden by co-resident wg)
    }
    BAR();
  }
  VM0();   // no DMA outlives this wg's LDS allocation
}

// XCD-aware swizzle for 256 wgs (0 mod 8 -> bijective): 32 contiguous tiles per XCD.
__device__ __forceinline__ void swizzle_mn256(int x, int& m0, int& n0) {
  const int wg = (x & 7) * 32 + (x >> 3);
  m0 = (wg >> 2) * 256;          // 64 m-tiles
  n0 = (wg & 3) * 256;           // 4 n-tiles
}

// z=0: k, z=1: v, z=2: r -> sigmoid.  acc = C^T of 32x32 tiles:
// C[m][n]: m = m0 + wm*128 + mi*32 + (lane&31); n = n0 + wn*64 + nj*32 + 8*g + 4*lh + j
__global__ __launch_bounds__(512, 4) void gemm_kvr(const unsigned short* __restrict__ kin,
    const unsigned short* __restrict__ vin, const unsigned short* __restrict__ rin,
    const unsigned short* __restrict__ Wbf,
    unsigned short* __restrict__ kb, unsigned short* __restrict__ vb,
    unsigned short* __restrict__ rb) {
  __shared__ unsigned short As[256 * 64];
  __shared__ unsigned short Bs[256 * 64];
  const int z = blockIdx.y;
  const unsigned short* Ag = z == 0 ? kin : (z == 1 ? vin : rin);
  const unsigned short* Bg = Wbf + (size_t)z * HH * HH;
  unsigned short* Cg = z == 0 ? kb : (z == 1 ? vb : rb);
  int m0, n0; swizzle_mn256(blockIdx.x, m0, n0);
  f32x16 acc[4][2] = {};
  gemm256(Ag, Bg, m0, n0, As, Bs, acc);
  const int lane = threadIdx.x & 63, w = threadIdx.x >> 6;
  const int wm = w >> 2, wn = w & 3, l31 = lane & 31, lh = lane >> 5;
  const bool sig = (z == 2);
#pragma unroll
  for (int mi = 0; mi < 4; ++mi) {
    const size_t mrow = (size_t)(m0 + wm * 128 + mi * 32 + l31) * HH;
#pragma unroll
    for (int nj = 0; nj < 2; ++nj) {
#pragma unroll
      for (int g = 0; g < 4; ++g) {
        const int ncol = n0 + wn * 64 + nj * 32 + 8 * g + 4 * lh;
        float v0 = acc[mi][nj][g * 4 + 0], v1 = acc[mi][nj][g * 4 + 1];
        float v2 = acc[mi][nj][g * 4 + 2], v3 = acc[mi][nj][g * 4 + 3];
        if (sig) {
          v0 = 1.0f / (1.0f + __expf(-v0)); v1 = 1.0f / (1.0f + __expf(-v1));
          v2 = 1.0f / (1.0f + __expf(-v2)); v3 = 1.0f / (1.0f + __expf(-v3));
        }
        ushort4 o; o.x = f2bf(v0); o.y = f2bf(v1); o.z = f2bf(v2); o.w = f2bf(v3);
        *(ushort4*)(Cg + mrow + ncol) = o;
      }
    }
  }
}

// out = rwkv @ Wo^T + bo  (fp32 out, float4 stores)
__global__ __launch_bounds__(512, 4) void gemm_o(const unsigned short* __restrict__ Ag,
    const unsigned short* __restrict__ Bg, const float* __restrict__ bias,
    float* __restrict__ C) {
  __shared__ unsigned short As[256 * 64];
  __shared__ unsigned short Bs[256 * 64];
  int m0, n0; swizzle_mn256(blockIdx.x, m0, n0);
  f32x16 acc[4][2] = {};
  gemm256(Ag, Bg, m0, n0, As, Bs, acc);
  const int lane = threadIdx.x & 63, w = threadIdx.x >> 6;
  const int wm = w >> 2, wn = w & 3, l31 = lane & 31, lh = lane >> 5;
#pragma unroll
  for (int mi = 0; mi < 4; ++mi) {
    const size_t mrow = (size_t)(m0 + wm * 128 + mi * 32 + l31) * HH;
#pragma unroll
    for (int nj = 0; nj < 2; ++nj) {
#pragma unroll
      for (int g = 0; g < 4; ++g) {
        const int ncol = n0 + wn * 64 + nj * 32 + 8 * g + 4 * lh;
        const float4 bv = *(const float4*)(bias + ncol);
        float4 ov;
        ov.x = acc[mi][nj][g * 4 + 0] + bv.x; ov.y = acc[mi][nj][g * 4 + 1] + bv.y;
        ov.z = acc[mi][nj][g * 4 + 2] + bv.z; ov.w = acc[mi][nj][g * 4 + 3] + bv.w;
        *(float4*)(C + mrow + ncol) = ov;
      }
    }
  }
}

// ---------------- WKV: chunk-parallel scan over T (8-wide vectorized) ----------------
__global__ __launch_bounds__(256) void wkv_part(const unsigned short* __restrict__ k,
    const unsigned short* __restrict__ v, const float* __restrict__ tdec,
    float* __restrict__ pnum, float* __restrict__ pden) {
  const int gid = blockIdx.x * 256 + threadIdx.x;   // 0 .. CC*BB*HH/8-1
  const int h0 = (gid & 127) * 8;
  const int b = (gid >> 7) & (BB - 1);
  const int c = gid >> 10;
  float td[8], num[8], den[8];
#pragma unroll
  for (int j = 0; j < 8; ++j) {
    td[j] = __expf(-__expf(tdec[h0 + j]));
    num[j] = 0.f; den[j] = 0.f;
  }
  size_t idx = (size_t)b * TT * HH + (size_t)(c * LL) * HH + h0;
#pragma unroll 4
  for (int i = 0; i < LL; ++i, idx += HH) {
    const u16x8 k8 = *(const u16x8*)(k + idx);
    const u16x8 v8 = *(const u16x8*)(v + idx);
#pragma unroll
    for (int j = 0; j < 8; ++j) {
      const float ek = __expf(bf2f(k8[j]));
      num[j] = td[j] * num[j] + ek * bf2f(v8[j]);
      den[j] = td[j] * den[j] + ek;
    }
  }
  const size_t o = (size_t)c * (BB * HH) + b * HH + h0;
#pragma unroll
  for (int j = 0; j < 8; ++j) { pnum[o + j] = num[j]; pden[o + j] = den[j]; }
}

__global__ __launch_bounds__(256) void wkv_scan(const float* __restrict__ tdec,
    float* __restrict__ pnum, float* __restrict__ pden) {
  const int bh = blockIdx.x * 256 + threadIdx.x;     // 0..8191
  const int h = bh & (HH - 1);
  const float ed = __expf(tdec[h]);
  const float tdL = __expf(-ed * (float)LL);         // td^LL exactly
  float num = 0.f, den = 0.f;
#pragma unroll 8
  for (int c = 0; c < CC; ++c) {
    const size_t o = (size_t)c * (BB * HH) + bh;
    const float tn = pnum[o], td_ = pden[o];
    pnum[o] = num; pden[o] = den;
    num = tdL * num + tn;
    den = tdL * den + td_;
  }
}

__global__ __launch_bounds__(256) void wkv_final(const unsigned short* __restrict__ k,
    const unsigned short* __restrict__ v, const unsigned short* __restrict__ r,
    const float* __restrict__ tdec, const float* __restrict__ tfst,
    const float* __restrict__ pnum, const float* __restrict__ pden,
    unsigned short* __restrict__ rwkv) {
  const int gid = blockIdx.x * 256 + threadIdx.x;   // 0 .. CC*BB*HH/8-1
  const int h0 = (gid & 127) * 8;
  const int b = (gid >> 7) & (BB - 1);
  const int c = gid >> 10;
  float td[8], etf[8], num[8], den[8];
  const size_t o = (size_t)c * (BB * HH) + b * HH + h0;
#pragma unroll
  for (int j = 0; j < 8; ++j) {
    td[j] = __expf(-__expf(tdec[h0 + j]));
    etf[j] = __expf(tfst[h0 + j]);
    num[j] = pnum[o + j]; den[j] = pden[o + j];
  }
  size_t idx = (size_t)b * TT * HH + (size_t)(c * LL) * HH + h0;
#pragma unroll 2
  for (int i = 0; i < LL; ++i, idx += HH) {
    const u16x8 k8 = *(const u16x8*)(k + idx);
    const u16x8 v8 = *(const u16x8*)(v + idx);
    const u16x8 r8 = *(const u16x8*)(r + idx);
    u16x8 o8;
#pragma unroll
    for (int j = 0; j < 8; ++j) {
      const float ek = __expf(bf2f(k8[j]));
      const float vt = bf2f(v8[j]);
      const float rt = bf2f(r8[j]);
      const float e = ek * etf[j];                   // exp(tf + k) = exp(k)*exp(tf)
      const float inv = __builtin_amdgcn_rcpf(den[j] + e);
      const float outv = (num[j] + e * vt) * inv;
      num[j] = td[j] * num[j] + ek * vt;
      den[j] = td[j] * den[j] + ek;
      o8[j] = f2bf(outv * rt);
    }
    *(u16x8*)(rwkv + idx) = o8;
  }
}

extern "C" void kernel_launch(void* const* d_in, const int* in_sizes, int n_in,
                              void* d_out, int out_size, void* d_ws, size_t ws_size,
                              hipStream_t stream) {
  (void)in_sizes; (void)n_in; (void)out_size; (void)ws_size;
  const float* x    = (const float*)d_in[0];
  const float* tdec = (const float*)d_in[1];
  const float* tfst = (const float*)d_in[2];
  const float* tmk  = (const float*)d_in[3];
  const float* tmv  = (const float*)d_in[4];
  const float* tmr  = (const float*)d_in[5];
  const float* Wk   = (const float*)d_in[6];
  const float* Wv   = (const float*)d_in[7];
  const float* Wr   = (const float*)d_in[8];
  const float* Wo   = (const float*)d_in[9];
  const float* bo   = (const float*)d_in[10];
  float* out = (float*)d_out;

  char* ws = (char*)d_ws;
  const size_t MiB = (size_t)1 << 20;
  unsigned short* Wbf = (unsigned short*)(ws);             //   8 MiB
  unsigned short* kin = (unsigned short*)(ws + 8 * MiB);   //  32 MiB
  unsigned short* vin = (unsigned short*)(ws + 40 * MiB);  //  32 MiB
  unsigned short* rin = (unsigned short*)(ws + 72 * MiB);  //  32 MiB
  unsigned short* rb  = (unsigned short*)(ws + 104 * MiB); //  32 MiB  (peak 136 MiB)
  // k,v bf16 staged in d_out (64 MiB fp32 buffer = 2 x 32 MiB bf16); dead before gemm_o writes.
  unsigned short* kb = (unsigned short*)out;
  unsigned short* vb = kb + (size_t)MM * HH;
  unsigned short* rwkv = kin;                  // kin dead after gemm_kvr
  float* pnum = (float*)(ws + 40 * MiB);       // vin dead after gemm_kvr (4 MiB @ CC=128)
  float* pden = (float*)(ws + 44 * MiB);       // (4 MiB)

  hipLaunchKernelGGL(conv_w, dim3(1024, 4), dim3(256), 0, stream, Wk, Wv, Wr, Wo, Wbf);
  hipLaunchKernelGGL(mix_kernel, dim3(16384), dim3(256), 0, stream,
                     x, tmk, tmv, tmr, kin, vin, rin);
  hipLaunchKernelGGL(gemm_kvr, dim3(256, 3), dim3(512), 0, stream,
                     kin, vin, rin, Wbf, kb, vb, rb);
  hipLaunchKernelGGL(wkv_part, dim3(512), dim3(256), 0, stream,
                     kb, vb, tdec, pnum, pden);
  hipLaunchKernelGGL(wkv_scan, dim3(32), dim3(256), 0, stream,
                     tdec, pnum, pden);
  hipLaunchKernelGGL(wkv_final, dim3(512), dim3(256), 0, stream,
                     kb, vb, rb, tdec, tfst, pnum, pden, rwkv);
  hipLaunchKernelGGL(gemm_o, dim3(256), dim3(512), 0, stream,
                     rwkv, Wbf + (size_t)3 * HH * HH, bo, out);
}

// Round 10
// 386.531 us; speedup vs baseline: 6.2412x; 6.2412x over previous
//
#include <hip/hip_runtime.h>
#include <hip/hip_bf16.h>
#include <cstdint>
#include <cstddef>

#define HH 1024
#define BB 8
#define TT 2048
#define MM (BB*TT)   // 16384
#define CC 128       // wkv chunks
#define LL (TT/CC)   // 16 steps per chunk

typedef __attribute__((ext_vector_type(8))) short bf16x8;
typedef __attribute__((ext_vector_type(8))) unsigned short u16x8;
typedef __attribute__((ext_vector_type(16))) float f32x16;

__device__ __forceinline__ unsigned short f2bf(float f) {
  union { float f; unsigned u; } v; v.f = f;
  return (unsigned short)((v.u + 0x7fffu + ((v.u >> 16) & 1u)) >> 16);  // RNE
}
__device__ __forceinline__ float bf2f(unsigned short s) {
  union { float f; unsigned u; } v; v.u = ((unsigned)s) << 16;
  return v.f;
}

__device__ __forceinline__ void load_lds16(const void* g, void* l) {
  __builtin_amdgcn_global_load_lds((const __attribute__((address_space(1))) void*)g,
                                   (__attribute__((address_space(3))) void*)l,
                                   16, 0, 0);
}

// ---------------- weight fp32 -> bf16 ----------------
__global__ __launch_bounds__(256) void conv_w(const float* __restrict__ Wk,
    const float* __restrict__ Wv, const float* __restrict__ Wr,
    const float* __restrict__ Wo, unsigned short* __restrict__ dst) {
  const int i = (blockIdx.x * 256 + threadIdx.x) * 4;
  const float* src = blockIdx.y == 0 ? Wk : blockIdx.y == 1 ? Wv : blockIdx.y == 2 ? Wr : Wo;
  const float4 v = *(const float4*)(src + i);
  ushort4 o; o.x = f2bf(v.x); o.y = f2bf(v.y); o.z = f2bf(v.z); o.w = f2bf(v.w);
  *(ushort4*)(dst + (size_t)blockIdx.y * HH * HH + i) = o;
}

// ---------------- time-shift + mix -> bf16 kin/vin/rin ----------------
__global__ __launch_bounds__(256) void mix_kernel(const float* __restrict__ x,
    const float* __restrict__ tmk, const float* __restrict__ tmv, const float* __restrict__ tmr,
    unsigned short* __restrict__ kin, unsigned short* __restrict__ vin,
    unsigned short* __restrict__ rin) {
  const int gid = blockIdx.x * 256 + threadIdx.x;
  const size_t e0 = (size_t)gid * 4;
  const int h = (int)(e0 & (HH - 1));
  const int t = (int)((e0 >> 10) & (TT - 1));
  const float4 xv = *(const float4*)(x + e0);
  float4 sv = make_float4(0.f, 0.f, 0.f, 0.f);
  if (t != 0) sv = *(const float4*)(x + e0 - HH);
  const float4 k4 = *(const float4*)(tmk + h);
  const float4 v4 = *(const float4*)(tmv + h);
  const float4 r4 = *(const float4*)(tmr + h);
  ushort4 ko, vo, ro;
  ko.x = f2bf(sv.x + k4.x * (xv.x - sv.x)); ko.y = f2bf(sv.y + k4.y * (xv.y - sv.y));
  ko.z = f2bf(sv.z + k4.z * (xv.z - sv.z)); ko.w = f2bf(sv.w + k4.w * (xv.w - sv.w));
  vo.x = f2bf(sv.x + v4.x * (xv.x - sv.x)); vo.y = f2bf(sv.y + v4.y * (xv.y - sv.y));
  vo.z = f2bf(sv.z + v4.z * (xv.z - sv.z)); vo.w = f2bf(sv.w + v4.w * (xv.w - sv.w));
  ro.x = f2bf(sv.x + r4.x * (xv.x - sv.x)); ro.y = f2bf(sv.y + r4.y * (xv.y - sv.y));
  ro.z = f2bf(sv.z + r4.z * (xv.z - sv.z)); ro.w = f2bf(sv.w + r4.w * (xv.w - sv.w));
  *(ushort4*)(kin + e0) = ko;
  *(ushort4*)(vin + e0) = vo;
  *(ushort4*)(rin + e0) = ro;
}

// ===== 256x256 GEMM core, r10: 32x32 frags + double-buffer + free-run 2-barrier =====
// r8 proved the 32x32-frag geometry (128x64/wave, 42.7 FLOP/B of LDS reads; pipes
// balanced: LDS ~2300 cy/CU/tile vs MFMA ~2070 cy/SIMD/tile) but its 8-phase lockstep
// serialized them (142us). r9 proved occupancy >2 waves/SIMD is impossible with the
// 128-reg acc (launch_bounds(512,4) -> 64-VGPR cap -> total spill).
// r10: keep (512,2); double-buffered 128KB LDS; per K-tile: issue next tile's 8 DMA
// loads, then 24 ds_reads + 32 MFMA FREE-RUNNING (no internal barriers/waits - the
// compiler's progressive lgkm releases MFMAs as reads land; 2 waves/SIMD co-schedule
// hides one wave's reads under the other's MFMA, m114). Only 2 barriers per tile.
// VM0 at boundary waits a DMA issued ~2300cy earlier (>900cy HBM latency -> ~free).
// WAR-safe: a buffer's reads are all consumed (drained) before the BAR preceding its
// restage. Staging/swizzle/rdS/mfmaS/epilogue identical to r8 (pass-verified).

#define BAR()   do { asm volatile("" ::: "memory"); __builtin_amdgcn_s_barrier(); \
                     asm volatile("" ::: "memory"); } while (0)
#define VM0()   asm volatile("s_waitcnt vmcnt(0)" ::: "memory")
#define PRIO1() __builtin_amdgcn_s_setprio(1)
#define PRIO0() __builtin_amdgcn_s_setprio(0)

__device__ __forceinline__ void stA(const unsigned short* __restrict__ Ag, int m0, int kt,
                                    unsigned short* buf, int h, int w, int rl, int scol) {
#pragma unroll
  for (int l = 0; l < 2; ++l) {
    const int row = l * 128 + h * 64 + w * 8;          // wave-uniform dest row base (0 mod 8)
    load_lds16(Ag + (size_t)(m0 + row + rl) * HH + kt + scol, buf + row * 64);
  }
}
__device__ __forceinline__ void stB(const unsigned short* __restrict__ Bg, int n0, int kt,
                                    unsigned short* buf, int h, int w, int rl, int scol) {
#pragma unroll
  for (int l = 0; l < 2; ++l) {
    const int row = (2 * (l * 2 + (w >> 2)) + h) * 32 + (w & 3) * 8;   // 0 mod 8
    load_lds16(Bg + (size_t)(n0 + row + rl) * HH + kt + scol, buf + row * 64);
  }
}

__device__ __forceinline__ bf16x8 rd1(const unsigned short* buf, int row, int kq, int swz) {
  return *(const bf16x8*)(buf + row * 64 + ((kq * 8) ^ swz));
}
// one K16-step's fragments: 6 ds_read_b128, consumption order
__device__ __forceinline__ void rdS(const unsigned short* bA, const unsigned short* bB,
                                    int wm, int wn, int l31, int kq, int swz,
                                    bf16x8 (&af)[4], bf16x8 (&bfr)[2]) {
  bfr[0] = rd1(bB, wn * 64 + l31, kq, swz);
  af[0]  = rd1(bA, wm * 128 + l31, kq, swz);
  bfr[1] = rd1(bB, wn * 64 + 32 + l31, kq, swz);
  af[1]  = rd1(bA, wm * 128 + 32 + l31, kq, swz);
  af[2]  = rd1(bA, wm * 128 + 64 + l31, kq, swz);
  af[3]  = rd1(bA, wm * 128 + 96 + l31, kq, swz);
}
// 8 MFMA of 32x32x16, swapped operands -> acc = C^T fragments. All independent.
__device__ __forceinline__ void mfmaS(f32x16 (&acc)[4][2], const bf16x8 (&af)[4],
                                      const bf16x8 (&bfr)[2]) {
#pragma unroll
  for (int mi = 0; mi < 4; ++mi)
#pragma unroll
    for (int nj = 0; nj < 2; ++nj)
      acc[mi][nj] = __builtin_amdgcn_mfma_f32_32x32x16_bf16(bfr[nj], af[mi],
                                                            acc[mi][nj], 0, 0, 0);
}

__device__ __forceinline__ void gemm256(const unsigned short* __restrict__ Ag,
                                        const unsigned short* __restrict__ Bg,
                                        const int m0, const int n0,
                                        unsigned short* As, unsigned short* Bs,
                                        f32x16 (&acc)[4][2]) {
  const int tid = threadIdx.x;
  const int lane = tid & 63;
  const int w = tid >> 6;
  const int wm = w >> 2, wn = w & 3;
  const int l31 = lane & 31, lh = lane >> 5;
  const int swz = (lane & 7) << 3;                 // read-side XOR (k-block ^= row&7)
  const int rl = lane >> 3;                        // stage dest row-in-8
  const int scol = ((lane & 7) ^ rl) * 8;          // pre-swizzled global source col
  unsigned short* const A0 = As;
  unsigned short* const A1 = As + 256 * 64;
  unsigned short* const B0 = Bs;
  unsigned short* const B1 = Bs + 256 * 64;
  bf16x8 af[4], bfr[2];

  // prologue: stage tile 0 into buf0; drain; barrier.
  stA(Ag, m0, 0, A0, 0, w, rl, scol);
  stA(Ag, m0, 0, A0, 1, w, rl, scol);
  stB(Bg, n0, 0, B0, 0, w, rl, scol);
  stB(Bg, n0, 0, B0, 1, w, rl, scol);
  VM0(); BAR();

#pragma unroll 1
  for (int t = 0; t < 16; ++t) {
    unsigned short* const Ac = (t & 1) ? A1 : A0;
    unsigned short* const Bc = (t & 1) ? B1 : B0;
    if (t < 15) {
      unsigned short* const An = (t & 1) ? A0 : A1;
      unsigned short* const Bn = (t & 1) ? B0 : B1;
      const int tn = (t + 1) * 64;
      stA(Ag, m0, tn, An, 0, w, rl, scol);
      stA(Ag, m0, tn, An, 1, w, rl, scol);
      stB(Bg, n0, tn, Bn, 0, w, rl, scol);
      stB(Bg, n0, tn, Bn, 1, w, rl, scol);
    }
    // free-run compute: 4 K16 substeps, no internal barriers/waits
#pragma unroll
    for (int s = 0; s < 4; ++s) {
      rdS(Ac, Bc, wm, wn, l31, s * 2 + lh, swz, af, bfr);
      PRIO1(); mfmaS(acc, af, bfr); PRIO0();
    }
    BAR();                       // all waves' reads of tile t done (consumed pre-BAR)
    if (t < 15) VM0();           // next tile's DMA landed (issued ~one tile ago)
    BAR();
  }
  VM0();   // no DMA outlives this wg's LDS allocation
}

// XCD-aware swizzle for 256 wgs (0 mod 8 -> bijective): 32 contiguous tiles per XCD.
__device__ __forceinline__ void swizzle_mn256(int x, int& m0, int& n0) {
  const int wg = (x & 7) * 32 + (x >> 3);
  m0 = (wg >> 2) * 256;          // 64 m-tiles
  n0 = (wg & 3) * 256;           // 4 n-tiles
}

// z=0: k, z=1: v, z=2: r -> sigmoid.  acc = C^T of 32x32 tiles:
// C[m][n]: m = m0 + wm*128 + mi*32 + (lane&31); n = n0 + wn*64 + nj*32 + 8*g + 4*lh + j
__global__ __launch_bounds__(512, 2) void gemm_kvr(const unsigned short* __restrict__ kin,
    const unsigned short* __restrict__ vin, const unsigned short* __restrict__ rin,
    const unsigned short* __restrict__ Wbf,
    unsigned short* __restrict__ kb, unsigned short* __restrict__ vb,
    unsigned short* __restrict__ rb) {
  __shared__ unsigned short As[2 * 256 * 64];
  __shared__ unsigned short Bs[2 * 256 * 64];
  const int z = blockIdx.y;
  const unsigned short* Ag = z == 0 ? kin : (z == 1 ? vin : rin);
  const unsigned short* Bg = Wbf + (size_t)z * HH * HH;
  unsigned short* Cg = z == 0 ? kb : (z == 1 ? vb : rb);
  int m0, n0; swizzle_mn256(blockIdx.x, m0, n0);
  f32x16 acc[4][2] = {};
  gemm256(Ag, Bg, m0, n0, As, Bs, acc);
  const int lane = threadIdx.x & 63, w = threadIdx.x >> 6;
  const int wm = w >> 2, wn = w & 3, l31 = lane & 31, lh = lane >> 5;
  const bool sig = (z == 2);
#pragma unroll
  for (int mi = 0; mi < 4; ++mi) {
    const size_t mrow = (size_t)(m0 + wm * 128 + mi * 32 + l31) * HH;
#pragma unroll
    for (int nj = 0; nj < 2; ++nj) {
#pragma unroll
      for (int g = 0; g < 4; ++g) {
        const int ncol = n0 + wn * 64 + nj * 32 + 8 * g + 4 * lh;
        float v0 = acc[mi][nj][g * 4 + 0], v1 = acc[mi][nj][g * 4 + 1];
        float v2 = acc[mi][nj][g * 4 + 2], v3 = acc[mi][nj][g * 4 + 3];
        if (sig) {
          v0 = 1.0f / (1.0f + __expf(-v0)); v1 = 1.0f / (1.0f + __expf(-v1));
          v2 = 1.0f / (1.0f + __expf(-v2)); v3 = 1.0f / (1.0f + __expf(-v3));
        }
        ushort4 o; o.x = f2bf(v0); o.y = f2bf(v1); o.z = f2bf(v2); o.w = f2bf(v3);
        *(ushort4*)(Cg + mrow + ncol) = o;
      }
    }
  }
}

// out = rwkv @ Wo^T + bo  (fp32 out, float4 stores)
__global__ __launch_bounds__(512, 2) void gemm_o(const unsigned short* __restrict__ Ag,
    const unsigned short* __restrict__ Bg, const float* __restrict__ bias,
    float* __restrict__ C) {
  __shared__ unsigned short As[2 * 256 * 64];
  __shared__ unsigned short Bs[2 * 256 * 64];
  int m0, n0; swizzle_mn256(blockIdx.x, m0, n0);
  f32x16 acc[4][2] = {};
  gemm256(Ag, Bg, m0, n0, As, Bs, acc);
  const int lane = threadIdx.x & 63, w = threadIdx.x >> 6;
  const int wm = w >> 2, wn = w & 3, l31 = lane & 31, lh = lane >> 5;
#pragma unroll
  for (int mi = 0; mi < 4; ++mi) {
    const size_t mrow = (size_t)(m0 + wm * 128 + mi * 32 + l31) * HH;
#pragma unroll
    for (int nj = 0; nj < 2; ++nj) {
#pragma unroll
      for (int g = 0; g < 4; ++g) {
        const int ncol = n0 + wn * 64 + nj * 32 + 8 * g + 4 * lh;
        const float4 bv = *(const float4*)(bias + ncol);
        float4 ov;
        ov.x = acc[mi][nj][g * 4 + 0] + bv.x; ov.y = acc[mi][nj][g * 4 + 1] + bv.y;
        ov.z = acc[mi][nj][g * 4 + 2] + bv.z; ov.w = acc[mi][nj][g * 4 + 3] + bv.w;
        *(float4*)(C + mrow + ncol) = ov;
      }
    }
  }
}

// ---------------- WKV: chunk-parallel scan over T (8-wide vectorized) ----------------
__global__ __launch_bounds__(256) void wkv_part(const unsigned short* __restrict__ k,
    const unsigned short* __restrict__ v, const float* __restrict__ tdec,
    float* __restrict__ pnum, float* __restrict__ pden) {
  const int gid = blockIdx.x * 256 + threadIdx.x;   // 0 .. CC*BB*HH/8-1
  const int h0 = (gid & 127) * 8;
  const int b = (gid >> 7) & (BB - 1);
  const int c = gid >> 10;
  float td[8], num[8], den[8];
#pragma unroll
  for (int j = 0; j < 8; ++j) {
    td[j] = __expf(-__expf(tdec[h0 + j]));
    num[j] = 0.f; den[j] = 0.f;
  }
  size_t idx = (size_t)b * TT * HH + (size_t)(c * LL) * HH + h0;
#pragma unroll 4
  for (int i = 0; i < LL; ++i, idx += HH) {
    const u16x8 k8 = *(const u16x8*)(k + idx);
    const u16x8 v8 = *(const u16x8*)(v + idx);
#pragma unroll
    for (int j = 0; j < 8; ++j) {
      const float ek = __expf(bf2f(k8[j]));
      num[j] = td[j] * num[j] + ek * bf2f(v8[j]);
      den[j] = td[j] * den[j] + ek;
    }
  }
  const size_t o = (size_t)c * (BB * HH) + b * HH + h0;
#pragma unroll
  for (int j = 0; j < 8; ++j) { pnum[o + j] = num[j]; pden[o + j] = den[j]; }
}

__global__ __launch_bounds__(256) void wkv_scan(const float* __restrict__ tdec,
    float* __restrict__ pnum, float* __restrict__ pden) {
  const int bh = blockIdx.x * 256 + threadIdx.x;     // 0..8191
  const int h = bh & (HH - 1);
  const float ed = __expf(tdec[h]);
  const float tdL = __expf(-ed * (float)LL);         // td^LL exactly
  float num = 0.f, den = 0.f;
#pragma unroll 8
  for (int c = 0; c < CC; ++c) {
    const size_t o = (size_t)c * (BB * HH) + bh;
    const float tn = pnum[o], td_ = pden[o];
    pnum[o] = num; pden[o] = den;
    num = tdL * num + tn;
    den = tdL * den + td_;
  }
}

__global__ __launch_bounds__(256) void wkv_final(const unsigned short* __restrict__ k,
    const unsigned short* __restrict__ v, const unsigned short* __restrict__ r,
    const float* __restrict__ tdec, const float* __restrict__ tfst,
    const float* __restrict__ pnum, const float* __restrict__ pden,
    unsigned short* __restrict__ rwkv) {
  const int gid = blockIdx.x * 256 + threadIdx.x;   // 0 .. CC*BB*HH/8-1
  const int h0 = (gid & 127) * 8;
  const int b = (gid >> 7) & (BB - 1);
  const int c = gid >> 10;
  float td[8], etf[8], num[8], den[8];
  const size_t o = (size_t)c * (BB * HH) + b * HH + h0;
#pragma unroll
  for (int j = 0; j < 8; ++j) {
    td[j] = __expf(-__expf(tdec[h0 + j]));
    etf[j] = __expf(tfst[h0 + j]);
    num[j] = pnum[o + j]; den[j] = pden[o + j];
  }
  size_t idx = (size_t)b * TT * HH + (size_t)(c * LL) * HH + h0;
#pragma unroll 2
  for (int i = 0; i < LL; ++i, idx += HH) {
    const u16x8 k8 = *(const u16x8*)(k + idx);
    const u16x8 v8 = *(const u16x8*)(v + idx);
    const u16x8 r8 = *(const u16x8*)(r + idx);
    u16x8 o8;
#pragma unroll
    for (int j = 0; j < 8; ++j) {
      const float ek = __expf(bf2f(k8[j]));
      const float vt = bf2f(v8[j]);
      const float rt = bf2f(r8[j]);
      const float e = ek * etf[j];                   // exp(tf + k) = exp(k)*exp(tf)
      const float inv = __builtin_amdgcn_rcpf(den[j] + e);
      const float outv = (num[j] + e * vt) * inv;
      num[j] = td[j] * num[j] + ek * vt;
      den[j] = td[j] * den[j] + ek;
      o8[j] = f2bf(outv * rt);
    }
    *(u16x8*)(rwkv + idx) = o8;
  }
}

extern "C" void kernel_launch(void* const* d_in, const int* in_sizes, int n_in,
                              void* d_out, int out_size, void* d_ws, size_t ws_size,
                              hipStream_t stream) {
  (void)in_sizes; (void)n_in; (void)out_size; (void)ws_size;
  const float* x    = (const float*)d_in[0];
  const float* tdec = (const float*)d_in[1];
  const float* tfst = (const float*)d_in[2];
  const float* tmk  = (const float*)d_in[3];
  const float* tmv  = (const float*)d_in[4];
  const float* tmr  = (const float*)d_in[5];
  const float* Wk   = (const float*)d_in[6];
  const float* Wv   = (const float*)d_in[7];
  const float* Wr   = (const float*)d_in[8];
  const float* Wo   = (const float*)d_in[9];
  const float* bo   = (const float*)d_in[10];
  float* out = (float*)d_out;

  char* ws = (char*)d_ws;
  const size_t MiB = (size_t)1 << 20;
  unsigned short* Wbf = (unsigned short*)(ws);             //   8 MiB
  unsigned short* kin = (unsigned short*)(ws + 8 * MiB);   //  32 MiB
  unsigned short* vin = (unsigned short*)(ws + 40 * MiB);  //  32 MiB
  unsigned short* rin = (unsigned short*)(ws + 72 * MiB);  //  32 MiB
  unsigned short* rb  = (unsigned short*)(ws + 104 * MiB); //  32 MiB  (peak 136 MiB)
  // k,v bf16 staged in d_out (64 MiB fp32 buffer = 2 x 32 MiB bf16); dead before gemm_o writes.
  unsigned short* kb = (unsigned short*)out;
  unsigned short* vb = kb + (size_t)MM * HH;
  unsigned short* rwkv = kin;                  // kin dead after gemm_kvr
  float* pnum = (float*)(ws + 40 * MiB);       // vin dead after gemm_kvr (4 MiB @ CC=128)
  float* pden = (float*)(ws + 44 * MiB);       // (4 MiB)

  hipLaunchKernelGGL(conv_w, dim3(1024, 4), dim3(256), 0, stream, Wk, Wv, Wr, Wo, Wbf);
  hipLaunchKernelGGL(mix_kernel, dim3(16384), dim3(256), 0, stream,
                     x, tmk, tmv, tmr, kin, vin, rin);
  hipLaunchKernelGGL(gemm_kvr, dim3(256, 3), dim3(512), 0, stream,
                     kin, vin, rin, Wbf, kb, vb, rb);
  hipLaunchKernelGGL(wkv_part, dim3(512), dim3(256), 0, stream,
                     kb, vb, tdec, pnum, pden);
  hipLaunchKernelGGL(wkv_scan, dim3(32), dim3(256), 0, stream,
                     tdec, pnum, pden);
  hipLaunchKernelGGL(wkv_final, dim3(512), dim3(256), 0, stream,
                     kb, vb, rb, tdec, tfst, pnum, pden, rwkv);
  hipLaunchKernelGGL(gemm_o, dim3(256), dim3(512), 0, stream,
                     rwkv, Wbf + (size_t)3 * HH * HH, bo, out);
}

// Round 11
// 348.632 us; speedup vs baseline: 6.9196x; 1.1087x over previous
//
#include <hip/hip_runtime.h>
#include <hip/hip_bf16.h>
#include <cstdint>
#include <cstddef>

#define HH 1024
#define BB 8
#define TT 2048
#define MM (BB*TT)   // 16384
#define CC 128       // wkv chunks
#define LL (TT/CC)   // 16 steps per chunk

typedef __attribute__((ext_vector_type(8))) short bf16x8;
typedef __attribute__((ext_vector_type(8))) unsigned short u16x8;
typedef __attribute__((ext_vector_type(4))) float f32x4;

__device__ __forceinline__ unsigned short f2bf(float f) {
  union { float f; unsigned u; } v; v.f = f;
  return (unsigned short)((v.u + 0x7fffu + ((v.u >> 16) & 1u)) >> 16);  // RNE
}
__device__ __forceinline__ float bf2f(unsigned short s) {
  union { float f; unsigned u; } v; v.u = ((unsigned)s) << 16;
  return v.f;
}

__device__ __forceinline__ void load_lds16(const void* g, void* l) {
  __builtin_amdgcn_global_load_lds((const __attribute__((address_space(1))) void*)g,
                                   (__attribute__((address_space(3))) void*)l,
                                   16, 0, 0);
}

// ---------------- weight fp32 -> bf16 ----------------
__global__ __launch_bounds__(256) void conv_w(const float* __restrict__ Wk,
    const float* __restrict__ Wv, const float* __restrict__ Wr,
    const float* __restrict__ Wo, unsigned short* __restrict__ dst) {
  const int i = (blockIdx.x * 256 + threadIdx.x) * 4;
  const float* src = blockIdx.y == 0 ? Wk : blockIdx.y == 1 ? Wv : blockIdx.y == 2 ? Wr : Wo;
  const float4 v = *(const float4*)(src + i);
  ushort4 o; o.x = f2bf(v.x); o.y = f2bf(v.y); o.z = f2bf(v.z); o.w = f2bf(v.w);
  *(ushort4*)(dst + (size_t)blockIdx.y * HH * HH + i) = o;
}

// ------- time-shift + mix, row-sequential (x read ~once: prev row kept in regs) -------
// block: batch b = bx>>7, t0 = (bx&127)*16; thread owns h-slice [tid*4, tid*4+4)
// and walks 16 consecutive t. Reads 17 rows per 16 outputs (6% overfetch) vs 2x before.
__global__ __launch_bounds__(256) void mix_kernel(const float* __restrict__ x,
    const float* __restrict__ tmk, const float* __restrict__ tmv, const float* __restrict__ tmr,
    unsigned short* __restrict__ kin, unsigned short* __restrict__ vin,
    unsigned short* __restrict__ rin) {
  const int b = blockIdx.x >> 7;
  const int t0 = (blockIdx.x & 127) * 16;
  const int h = threadIdx.x * 4;
  const float4 k4 = *(const float4*)(tmk + h);
  const float4 v4 = *(const float4*)(tmv + h);
  const float4 r4 = *(const float4*)(tmr + h);
  size_t base = (size_t)b * TT * HH + (size_t)t0 * HH + h;
  float4 sv = make_float4(0.f, 0.f, 0.f, 0.f);
  if (t0 != 0) sv = *(const float4*)(x + base - HH);
#pragma unroll 4
  for (int i = 0; i < 16; ++i) {
    const float4 xv = *(const float4*)(x + base);
    ushort4 ko, vo, ro;
    ko.x = f2bf(sv.x + k4.x * (xv.x - sv.x)); ko.y = f2bf(sv.y + k4.y * (xv.y - sv.y));
    ko.z = f2bf(sv.z + k4.z * (xv.z - sv.z)); ko.w = f2bf(sv.w + k4.w * (xv.w - sv.w));
    vo.x = f2bf(sv.x + v4.x * (xv.x - sv.x)); vo.y = f2bf(sv.y + v4.y * (xv.y - sv.y));
    vo.z = f2bf(sv.z + v4.z * (xv.z - sv.z)); vo.w = f2bf(sv.w + v4.w * (xv.w - sv.w));
    ro.x = f2bf(sv.x + r4.x * (xv.x - sv.x)); ro.y = f2bf(sv.y + r4.y * (xv.y - sv.y));
    ro.z = f2bf(sv.z + r4.z * (xv.z - sv.z)); ro.w = f2bf(sv.w + r4.w * (xv.w - sv.w));
    *(ushort4*)(kin + base) = ko;
    *(ushort4*)(vin + base) = vo;
    *(ushort4*)(rin + base) = ro;
    sv = xv; base += HH;
  }
}

// ==== 256x256 GEMM core, r11: r7 core with ONE barrier per phase (end-of-phase) ====
// r4/r7 post-mortem (corrected arithmetic): per iter LDS 4608 cy/CU ~ MFMA 4966 cy/CU
// -> balanced pipes, but the 2-barrier lockstep SERIALIZED them (sum ~12k cy/iter).
// Hazard re-derivation: every stage(p) overwrites rows last read in phase <= p-1, and
// every read(p) is consumed by MFMA(p) (lgkm-drained before the wave reaches BAR(p)).
// => the pre-MFMA barrier is unnecessary. One end-of-phase barrier keeps all WAR/RAW
// guarantees while letting wave A's MFMA overlap wave B's reads (m114), at ZERO extra
// registers (r6's read-ahead died on spill). VM6 semantics unchanged (no VM ops issued
// in between; placed after MFMA so DMA drains under compute).
// Staging/3-bit swizzle (0 conflicts, r4) and packed C^T epilogue (r5+) carried over.

#define BAR()   do { asm volatile("" ::: "memory"); __builtin_amdgcn_s_barrier(); \
                     asm volatile("" ::: "memory"); } while (0)
#define VM6()   asm volatile("s_waitcnt vmcnt(6)" ::: "memory")
#define VM0()   asm volatile("s_waitcnt vmcnt(0)" ::: "memory")
#define PRIO1() __builtin_amdgcn_s_setprio(1)
#define PRIO0() __builtin_amdgcn_s_setprio(0)

__device__ __forceinline__ void stA(const unsigned short* __restrict__ Ag, int m0, int kt,
                                    unsigned short* buf, int h, int w, int rl, int scol) {
#pragma unroll
  for (int l = 0; l < 2; ++l) {
    const int row = l * 128 + h * 64 + w * 8;          // wave-uniform dest row base (0 mod 8)
    load_lds16(Ag + (size_t)(m0 + row + rl) * HH + kt + scol, buf + row * 64);
  }
}
__device__ __forceinline__ void stB(const unsigned short* __restrict__ Bg, int n0, int kt,
                                    unsigned short* buf, int h, int w, int rl, int scol) {
#pragma unroll
  for (int l = 0; l < 2; ++l) {
    const int row = (2 * (l * 2 + (w >> 2)) + h) * 32 + (w & 3) * 8;   // 0 mod 8
    load_lds16(Bg + (size_t)(n0 + row + rl) * HH + kt + scol, buf + row * 64);
  }
}

// read one A half (MH), kk-outer (consumption order): 8 x ds_read_b128
template<int MH>
__device__ __forceinline__ void rdA(const unsigned short* buf, bf16x8 (&af)[4][2],
                                    int wm, int l15, int kq, int swz) {
#pragma unroll
  for (int kk = 0; kk < 2; ++kk)
#pragma unroll
    for (int fm = 0; fm < 4; ++fm)
      af[fm][kk] = *(const bf16x8*)(buf + (wm * 128 + MH * 64 + fm * 16 + l15) * 64
                                        + ((kk * 32 + kq * 8) ^ swz));
}
// read one B half (NH), kk-outer: 4 x ds_read_b128
template<int NH>
__device__ __forceinline__ void rdB(const unsigned short* buf, bf16x8 (&bfr)[2][2][2],
                                    int wn, int l15, int kq, int swz) {
#pragma unroll
  for (int kk = 0; kk < 2; ++kk)
#pragma unroll
    for (int fn = 0; fn < 2; ++fn)
      bfr[NH][fn][kk] = *(const bf16x8*)(buf + (wn * 64 + NH * 32 + fn * 16 + l15) * 64
                                             + ((kk * 32 + kq * 8) ^ swz));
}
// 16 MFMA, kk-outer (matches read order). Operands SWAPPED -> acc = C^T fragments.
template<int MH, int NH>
__device__ __forceinline__ void mfmaQ(f32x4 (&acc)[8][4], const bf16x8 (&af)[4][2],
                                      const bf16x8 (&bfr)[2][2][2]) {
#pragma unroll
  for (int kk = 0; kk < 2; ++kk)
#pragma unroll
    for (int fm = 0; fm < 4; ++fm)
#pragma unroll
      for (int fn = 0; fn < 2; ++fn)
        acc[MH * 4 + fm][NH * 2 + fn] = __builtin_amdgcn_mfma_f32_16x16x32_bf16(
            bfr[NH][fn][kk], af[fm][kk], acc[MH * 4 + fm][NH * 2 + fn], 0, 0, 0);
}

__device__ __forceinline__ void gemm256(const unsigned short* __restrict__ Ag,
                                        const unsigned short* __restrict__ Bg,
                                        const int m0, const int n0,
                                        unsigned short* As, unsigned short* Bs,
                                        f32x4 (&acc)[8][4]) {
  const int tid = threadIdx.x;
  const int lane = tid & 63;
  const int w = tid >> 6;
  const int wm = w >> 2, wn = w & 3;
  const int l15 = lane & 15, kq = lane >> 4;
  const int swz = (l15 & 7) << 3;                 // read-side XOR (k-block ^= row&7)
  const int rl = lane >> 3;                        // stage dest row-in-8
  const int scol = ((lane & 7) ^ rl) * 8;          // pre-swizzled global source col
  unsigned short* const A0 = As;
  unsigned short* const A1 = As + 256 * 64;
  unsigned short* const B0 = Bs;
  unsigned short* const B1 = Bs + 256 * 64;
  bf16x8 af[4][2], bfr[2][2][2];

  // prologue: buf0 tile0 (8 loads) + buf1 tile1 {A1h0,B1h0,B1h1} (6 loads); drain buf0.
  stA(Ag, m0, 0, A0, 0, w, rl, scol);
  stB(Bg, n0, 0, B0, 0, w, rl, scol);
  stB(Bg, n0, 0, B0, 1, w, rl, scol);
  stA(Ag, m0, 0, A0, 1, w, rl, scol);
  stA(Ag, m0, 64, A1, 0, w, rl, scol);
  stB(Bg, n0, 64, B1, 0, w, rl, scol);
  stB(Bg, n0, 64, B1, 1, w, rl, scol);
  VM6(); BAR();

#pragma unroll 1
  for (int i = 0; i < 8; ++i) {
    const int tb1 = ((2 * i + 1) * 64) & (HH - 1);  // buf1 current tile (A1h1 staged ph1)
    const int tn0 = ((2 * i + 2) * 64) & (HH - 1);  // buf0 next tile
    const int tn1 = ((2 * i + 3) * 64) & (HH - 1);  // buf1 next tile (wraps @end, harmless)
    // ph1: read B0-nh0 + A0-mh0; stage buf1.A-h1 (A1-h1 last read ph7 prev iter)
    rdB<0>(B0, bfr, wn, l15, kq, swz);
    rdA<0>(A0, af, wm, l15, kq, swz);
    stA(Ag, m0, tb1, A1, 1, w, rl, scol);
    PRIO1(); mfmaQ<0, 0>(acc, af, bfr); PRIO0(); BAR();
    // ph2: read B0-nh1; stage buf0.A-h0 (last read ph1)
    rdB<1>(B0, bfr, wn, l15, kq, swz);
    stA(Ag, m0, tn0, A0, 0, w, rl, scol);
    PRIO1(); mfmaQ<0, 1>(acc, af, bfr); PRIO0(); BAR();
    // ph3: read A0-mh1; stage buf0.B-h0 (last read ph1)
    rdA<1>(A0, af, wm, l15, kq, swz);
    stB(Bg, n0, tn0, B0, 0, w, rl, scol);
    PRIO1(); mfmaQ<1, 1>(acc, af, bfr); PRIO0(); BAR();
    // ph4: no reads; stage buf0.B-h1 (last read ph2); VM6 drains buf1 tile under MFMA
    stB(Bg, n0, tn0, B0, 1, w, rl, scol);
    PRIO1(); mfmaQ<1, 0>(acc, af, bfr); PRIO0(); VM6(); BAR();
    // ph5: read B1-nh0 + A1-mh0; stage buf0.A-h1 (last read ph3)
    rdB<0>(B1, bfr, wn, l15, kq, swz);
    rdA<0>(A1, af, wm, l15, kq, swz);
    stA(Ag, m0, tn0, A0, 1, w, rl, scol);
    PRIO1(); mfmaQ<0, 0>(acc, af, bfr); PRIO0(); BAR();
    // ph6: read B1-nh1; stage buf1.A-h0 (last read ph5)
    rdB<1>(B1, bfr, wn, l15, kq, swz);
    stA(Ag, m0, tn1, A1, 0, w, rl, scol);
    PRIO1(); mfmaQ<0, 1>(acc, af, bfr); PRIO0(); BAR();
    // ph7: read A1-mh1; stage buf1.B-h0 (last read ph5)
    rdA<1>(A1, af, wm, l15, kq, swz);
    stB(Bg, n0, tn1, B1, 0, w, rl, scol);
    PRIO1(); mfmaQ<1, 1>(acc, af, bfr); PRIO0(); BAR();
    // ph8: no reads; stage buf1.B-h1 (last read ph6); VM6 drains buf0-next under MFMA
    stB(Bg, n0, tn1, B1, 1, w, rl, scol);
    PRIO1(); mfmaQ<1, 0>(acc, af, bfr); PRIO0(); VM6(); BAR();
  }
  // no DMA may outlive this workgroup's LDS allocation
  VM0();
}

// XCD-aware swizzle for 256 wgs (0 mod 8 -> bijective): 32 contiguous tiles per XCD.
__device__ __forceinline__ void swizzle_mn256(int x, int& m0, int& n0) {
  const int wg = (x & 7) * 32 + (x >> 3);
  m0 = (wg >> 2) * 256;          // 64 m-tiles
  n0 = (wg & 3) * 256;           // 4 n-tiles
}

// z=0: k, z=1: v, z=2: r -> sigmoid
// acc = C^T fragments: C[m][n], m = m0+wm*128+fm*16+l15, n = n0+wn*64+fn*16+lq*4+j
__global__ __launch_bounds__(512, 2) void gemm_kvr(const unsigned short* __restrict__ kin,
    const unsigned short* __restrict__ vin, const unsigned short* __restrict__ rin,
    const unsigned short* __restrict__ Wbf,
    unsigned short* __restrict__ kb, unsigned short* __restrict__ vb,
    unsigned short* __restrict__ rb) {
  __shared__ unsigned short As[2 * 256 * 64];
  __shared__ unsigned short Bs[2 * 256 * 64];
  const int z = blockIdx.y;
  const unsigned short* Ag = z == 0 ? kin : (z == 1 ? vin : rin);
  const unsigned short* Bg = Wbf + (size_t)z * HH * HH;
  unsigned short* Cg = z == 0 ? kb : (z == 1 ? vb : rb);
  int m0, n0; swizzle_mn256(blockIdx.x, m0, n0);
  f32x4 acc[8][4] = {};
  gemm256(Ag, Bg, m0, n0, As, Bs, acc);
  const int lane = threadIdx.x & 63, w = threadIdx.x >> 6;
  const int wm = w >> 2, wn = w & 3, l15 = lane & 15, lq = lane >> 4;
  const bool sig = (z == 2);
#pragma unroll
  for (int fm = 0; fm < 8; ++fm) {
    const size_t mrow = (size_t)(m0 + wm * 128 + fm * 16 + l15) * HH;
#pragma unroll
    for (int fn = 0; fn < 4; ++fn) {
      const int ncol = n0 + wn * 64 + fn * 16 + lq * 4;
      float v0 = acc[fm][fn][0], v1 = acc[fm][fn][1];
      float v2 = acc[fm][fn][2], v3 = acc[fm][fn][3];
      if (sig) {
        v0 = 1.0f / (1.0f + __expf(-v0)); v1 = 1.0f / (1.0f + __expf(-v1));
        v2 = 1.0f / (1.0f + __expf(-v2)); v3 = 1.0f / (1.0f + __expf(-v3));
      }
      ushort4 o; o.x = f2bf(v0); o.y = f2bf(v1); o.z = f2bf(v2); o.w = f2bf(v3);
      *(ushort4*)(Cg + mrow + ncol) = o;
    }
  }
}

// out = rwkv @ Wo^T + bo  (fp32 out, float4 stores)
__global__ __launch_bounds__(512, 2) void gemm_o(const unsigned short* __restrict__ Ag,
    const unsigned short* __restrict__ Bg, const float* __restrict__ bias,
    float* __restrict__ C) {
  __shared__ unsigned short As[2 * 256 * 64];
  __shared__ unsigned short Bs[2 * 256 * 64];
  int m0, n0; swizzle_mn256(blockIdx.x, m0, n0);
  f32x4 acc[8][4] = {};
  gemm256(Ag, Bg, m0, n0, As, Bs, acc);
  const int lane = threadIdx.x & 63, w = threadIdx.x >> 6;
  const int wm = w >> 2, wn = w & 3, l15 = lane & 15, lq = lane >> 4;
#pragma unroll
  for (int fm = 0; fm < 8; ++fm) {
    const size_t mrow = (size_t)(m0 + wm * 128 + fm * 16 + l15) * HH;
#pragma unroll
    for (int fn = 0; fn < 4; ++fn) {
      const int ncol = n0 + wn * 64 + fn * 16 + lq * 4;
      const float4 bv = *(const float4*)(bias + ncol);
      float4 ov;
      ov.x = acc[fm][fn][0] + bv.x; ov.y = acc[fm][fn][1] + bv.y;
      ov.z = acc[fm][fn][2] + bv.z; ov.w = acc[fm][fn][3] + bv.w;
      *(float4*)(C + mrow + ncol) = ov;
    }
  }
}

// ---------------- WKV: chunk-parallel scan over T (8-wide vectorized) ----------------
__global__ __launch_bounds__(256) void wkv_part(const unsigned short* __restrict__ k,
    const unsigned short* __restrict__ v, const float* __restrict__ tdec,
    float* __restrict__ pnum, float* __restrict__ pden) {
  const int gid = blockIdx.x * 256 + threadIdx.x;   // 0 .. CC*BB*HH/8-1
  const int h0 = (gid & 127) * 8;
  const int b = (gid >> 7) & (BB - 1);
  const int c = gid >> 10;
  float td[8], num[8], den[8];
#pragma unroll
  for (int j = 0; j < 8; ++j) {
    td[j] = __expf(-__expf(tdec[h0 + j]));
    num[j] = 0.f; den[j] = 0.f;
  }
  size_t idx = (size_t)b * TT * HH + (size_t)(c * LL) * HH + h0;
#pragma unroll 4
  for (int i = 0; i < LL; ++i, idx += HH) {
    const u16x8 k8 = *(const u16x8*)(k + idx);
    const u16x8 v8 = *(const u16x8*)(v + idx);
#pragma unroll
    for (int j = 0; j < 8; ++j) {
      const float ek = __expf(bf2f(k8[j]));
      num[j] = td[j] * num[j] + ek * bf2f(v8[j]);
      den[j] = td[j] * den[j] + ek;
    }
  }
  const size_t o = (size_t)c * (BB * HH) + b * HH + h0;
#pragma unroll
  for (int j = 0; j < 8; ++j) { pnum[o + j] = num[j]; pden[o + j] = den[j]; }
}

__global__ __launch_bounds__(256) void wkv_scan(const float* __restrict__ tdec,
    float* __restrict__ pnum, float* __restrict__ pden) {
  const int bh = blockIdx.x * 256 + threadIdx.x;     // 0..8191
  const int h = bh & (HH - 1);
  const float ed = __expf(tdec[h]);
  const float tdL = __expf(-ed * (float)LL);         // td^LL exactly
  float num = 0.f, den = 0.f;
#pragma unroll 8
  for (int c = 0; c < CC; ++c) {
    const size_t o = (size_t)c * (BB * HH) + bh;
    const float tn = pnum[o], td_ = pden[o];
    pnum[o] = num; pden[o] = den;
    num = tdL * num + tn;
    den = tdL * den + td_;
  }
}

__global__ __launch_bounds__(256) void wkv_final(const unsigned short* __restrict__ k,
    const unsigned short* __restrict__ v, const unsigned short* __restrict__ r,
    const float* __restrict__ tdec, const float* __restrict__ tfst,
    const float* __restrict__ pnum, const float* __restrict__ pden,
    unsigned short* __restrict__ rwkv) {
  const int gid = blockIdx.x * 256 + threadIdx.x;   // 0 .. CC*BB*HH/8-1
  const int h0 = (gid & 127) * 8;
  const int b = (gid >> 7) & (BB - 1);
  const int c = gid >> 10;
  float td[8], etf[8], num[8], den[8];
  const size_t o = (size_t)c * (BB * HH) + b * HH + h0;
#pragma unroll
  for (int j = 0; j < 8; ++j) {
    td[j] = __expf(-__expf(tdec[h0 + j]));
    etf[j] = __expf(tfst[h0 + j]);
    num[j] = pnum[o + j]; den[j] = pden[o + j];
  }
  size_t idx = (size_t)b * TT * HH + (size_t)(c * LL) * HH + h0;
#pragma unroll 2
  for (int i = 0; i < LL; ++i, idx += HH) {
    const u16x8 k8 = *(const u16x8*)(k + idx);
    const u16x8 v8 = *(const u16x8*)(v + idx);
    const u16x8 r8 = *(const u16x8*)(r + idx);
    u16x8 o8;
#pragma unroll
    for (int j = 0; j < 8; ++j) {
      const float ek = __expf(bf2f(k8[j]));
      const float vt = bf2f(v8[j]);
      const float rt = bf2f(r8[j]);
      const float e = ek * etf[j];                   // exp(tf + k) = exp(k)*exp(tf)
      const float inv = __builtin_amdgcn_rcpf(den[j] + e);
      const float outv = (num[j] + e * vt) * inv;
      num[j] = td[j] * num[j] + ek * vt;
      den[j] = td[j] * den[j] + ek;
      o8[j] = f2bf(outv * rt);
    }
    *(u16x8*)(rwkv + idx) = o8;
  }
}

extern "C" void kernel_launch(void* const* d_in, const int* in_sizes, int n_in,
                              void* d_out, int out_size, void* d_ws, size_t ws_size,
                              hipStream_t stream) {
  (void)in_sizes; (void)n_in; (void)out_size; (void)ws_size;
  const float* x    = (const float*)d_in[0];
  const float* tdec = (const float*)d_in[1];
  const float* tfst = (const float*)d_in[2];
  const float* tmk  = (const float*)d_in[3];
  const float* tmv  = (const float*)d_in[4];
  const float* tmr  = (const float*)d_in[5];
  const float* Wk   = (const float*)d_in[6];
  const float* Wv   = (const float*)d_in[7];
  const float* Wr   = (const float*)d_in[8];
  const float* Wo   = (const float*)d_in[9];
  const float* bo   = (const float*)d_in[10];
  float* out = (float*)d_out;

  char* ws = (char*)d_ws;
  const size_t MiB = (size_t)1 << 20;
  unsigned short* Wbf = (unsigned short*)(ws);             //   8 MiB
  unsigned short* kin = (unsigned short*)(ws + 8 * MiB);   //  32 MiB
  unsigned short* vin = (unsigned short*)(ws + 40 * MiB);  //  32 MiB
  unsigned short* rin = (unsigned short*)(ws + 72 * MiB);  //  32 MiB
  unsigned short* rb  = (unsigned short*)(ws + 104 * MiB); //  32 MiB  (peak 136 MiB)
  // k,v bf16 staged in d_out (64 MiB fp32 buffer = 2 x 32 MiB bf16); dead before gemm_o writes.
  unsigned short* kb = (unsigned short*)out;
  unsigned short* vb = kb + (size_t)MM * HH;
  unsigned short* rwkv = kin;                  // kin dead after gemm_kvr
  float* pnum = (float*)(ws + 40 * MiB);       // vin dead after gemm_kvr (4 MiB @ CC=128)
  float* pden = (float*)(ws + 44 * MiB);       // (4 MiB)

  hipLaunchKernelGGL(conv_w, dim3(1024, 4), dim3(256), 0, stream, Wk, Wv, Wr, Wo, Wbf);
  hipLaunchKernelGGL(mix_kernel, dim3(1024), dim3(256), 0, stream,
                     x, tmk, tmv, tmr, kin, vin, rin);
  hipLaunchKernelGGL(gemm_kvr, dim3(256, 3), dim3(512), 0, stream,
                     kin, vin, rin, Wbf, kb, vb, rb);
  hipLaunchKernelGGL(wkv_part, dim3(512), dim3(256), 0, stream,
                     kb, vb, tdec, pnum, pden);
  hipLaunchKernelGGL(wkv_scan, dim3(32), dim3(256), 0, stream,
                     tdec, pnum, pden);
  hipLaunchKernelGGL(wkv_final, dim3(512), dim3(256), 0, stream,
                     kb, vb, rb, tdec, tfst, pnum, pden, rwkv);
  hipLaunchKernelGGL(gemm_o, dim3(256), dim3(512), 0, stream,
                     rwkv, Wbf + (size_t)3 * HH * HH, bo, out);
}